// Round 2
// baseline (1219.550 us; speedup 1.0000x reference)
//
#include <hip/hip_runtime.h>
#include <cstdint>
#include <cstddef>

// Problem constants
#define B_   16
#define N_   576
#define D_   768
#define H_   8
#define HD_  96
#define DF_  3072
#define R_   (B_*N_)               // 9216 rows
#define SCALE_F 0.10206207261596575f  // 96^-0.5

typedef __bf16 bf16;
typedef __attribute__((ext_vector_type(8))) __bf16 bf16x8;
typedef __attribute__((ext_vector_type(4))) float  f32x4;

__device__ __forceinline__ void gld_lds16(const void* g, void* l) {
  __builtin_amdgcn_global_load_lds((const __attribute__((address_space(1))) void*)g,
                                   (__attribute__((address_space(3))) void*)l,
                                   16, 0, 0);
}
__device__ __forceinline__ void nt_f32(float* p, float v) { __builtin_nontemporal_store(v, p); }
__device__ __forceinline__ void nt_u64(void* p, unsigned long long v) { __builtin_nontemporal_store(v, (unsigned long long*)p); }
__device__ __forceinline__ void nt_bf16(bf16* p, float v) {
  bf16 h = (bf16)v; unsigned short u; __builtin_memcpy(&u, &h, 2);
  __builtin_nontemporal_store(u, (unsigned short*)p);
}

// ---------------- prep kernels ----------------
__global__ void cast_f32_bf16_k(const float* __restrict__ x, bf16* __restrict__ y, int n4) {
  int i = blockIdx.x*256 + threadIdx.x;
  if (i >= n4) return;
  f32x4 v = ((const f32x4*)x)[i];
  union { bf16 h[4]; unsigned long long q; } u;
  u.h[0] = (bf16)v[0]; u.h[1] = (bf16)v[1]; u.h[2] = (bf16)v[2]; u.h[3] = (bf16)v[3];
  nt_u64((unsigned long long*)y + i, u.q);
}

// WT[c][r] = (bf16)W[r][c];  rows, cols multiples of 32
__global__ void transpose_cast_k(const float* __restrict__ W, bf16* __restrict__ WT,
                                 int rows, int cols) {
  __shared__ float tile[32][33];
  int cb = blockIdx.x*32, rb = blockIdx.y*32;
  int tx = threadIdx.x, ty = threadIdx.y;   // block (32,8)
  #pragma unroll
  for (int i=0;i<32;i+=8)
    tile[ty+i][tx] = W[(size_t)(rb+ty+i)*cols + cb+tx];
  __syncthreads();
  #pragma unroll
  for (int i=0;i<32;i+=8)
    WT[(size_t)(cb+ty+i)*rows + rb+tx] = (bf16)tile[tx][ty+i];
}

__global__ void concat_bias_k(const float* a, const float* b, const float* c, float* o) {
  int i = blockIdx.x*256 + threadIdx.x;
  if (i < 768) o[i] = a[i];
  else if (i < 1536) o[i] = b[i-768];
  else if (i < 2304) o[i] = c[i-1536];
}

// ---------------- BT-GEMM: C[M,N] = A[M,K] @ Bt[N,K]^T + bias ----------------
// 128x128 tile, BK=64, 256 thr (4 waves 2x2), global_load_lds w=16,
// fragment-linear LDS layout: byte = blk16*2048 + k8*256 + r16*16  (zero bank conflicts)
// EPI: 2 = f32 out, 3 = gelu->bf16, 4 = fused QKV routing (Q,K row-major; V -> V^T layout)
template<int EPI>
__global__ __launch_bounds__(256, 2) void gemm_bt_k(
    const bf16* __restrict__ A, const bf16* __restrict__ Bt,
    const float* __restrict__ bias, float* __restrict__ outF,
    bf16* __restrict__ outB, bf16* __restrict__ outK, bf16* __restrict__ outVT,
    int M, int Nn, int K)
{
  __shared__ __align__(16) char lds[32768];
  char* As = lds; char* Bs = lds + 16384;
  const int t = threadIdx.x;
  const int lane = t & 63, w = t >> 6, g = lane >> 4, r = lane & 15;
  const int wr = w >> 1, wc = w & 1;
  const int rt = blockIdx.x, ct = blockIdx.y;
  const size_t a0 = (size_t)rt*128, b0 = (size_t)ct*128;

  f32x4 acc[4][4];
  #pragma unroll
  for (int m=0;m<4;++m)
    #pragma unroll
    for (int n=0;n<4;++n) acc[m][n] = (f32x4){0.f,0.f,0.f,0.f};

  const int k8    = (t>>4)&7;
  const int rbase = ((t>>7)<<4) + (t&15);
  const bf16* Abase = A  + (a0 + rbase)*(size_t)K + k8*8;
  const bf16* Bbase = Bt + (b0 + rbase)*(size_t)K + k8*8;
  const size_t rstep = (size_t)32*K;
  const int nkb = K >> 6;

  for (int kb = 0; kb < nkb; ++kb) {
    const size_t ko = (size_t)kb*64;
    #pragma unroll
    for (int i=0;i<4;++i) {
      gld_lds16(Abase + (size_t)i*rstep + ko, As + i*4096 + t*16);
      gld_lds16(Bbase + (size_t)i*rstep + ko, Bs + i*4096 + t*16);
    }
    __syncthreads();
    #pragma unroll
    for (int kk=0;kk<2;++kk) {
      bf16x8 af[4], bfr[4];
      #pragma unroll
      for (int m=0;m<4;++m) af[m]  = *(const bf16x8*)(As + (wr*4+m)*2048 + kk*1024 + lane*16);
      #pragma unroll
      for (int n=0;n<4;++n) bfr[n] = *(const bf16x8*)(Bs + (wc*4+n)*2048 + kk*1024 + lane*16);
      #pragma unroll
      for (int m=0;m<4;++m)
        #pragma unroll
        for (int n=0;n<4;++n)
          acc[m][n] = __builtin_amdgcn_mfma_f32_16x16x32_bf16(af[m], bfr[n], acc[m][n], 0, 0, 0);
    }
    __syncthreads();
  }

  const int colb = ct*128 + wc*64;
  const int rowb = rt*128 + wr*64;
  #pragma unroll
  for (int n=0;n<4;++n) {
    const int col = colb + n*16 + r;
    const float bc = bias[col];
    #pragma unroll
    for (int m=0;m<4;++m) {
      const int row0 = rowb + m*16 + g*4;
      #pragma unroll
      for (int j=0;j<4;++j) {
        const int row = row0 + j;
        float v = acc[m][n][j] + bc;
        if (EPI == 2) {
          nt_f32(outF + (size_t)row*Nn + col, v);
        } else if (EPI == 3) {                  // exact gelu -> bf16
          float ge = 0.5f*v*(1.0f + erff(v*0.70710678118f));
          nt_bf16(outB + (size_t)row*Nn + col, ge);
        } else {                                // EPI==4: QKV routing
          if (col < 768) {
            nt_bf16(outB + (size_t)row*768 + col, v);
          } else if (col < 1536) {
            nt_bf16(outK + (size_t)row*768 + (col-768), v);
          } else {
            const int bb = row / N_, nn = row - bb*N_;
            nt_bf16(outVT + ((size_t)bb*D_ + (col-1536))*N_ + nn, v);
          }
        }
      }
    }
  }
  (void)M;
}

// ---------------- attention ----------------
// 1-D grid 2304: qt = blockIdx.x>>7 (18 q-tiles), bh = blockIdx.x&127 (b*8+h).
// blockIdx%8 == h  ->  all q-tiles of one head land on one XCD (L2 locality).
// Block = 128 thr (2 waves), each wave owns 16 q-rows; full 576-col S in 36 f32x4 accs.

// Kernel A (block s=1): O2 = softmax(Q2 K1^T) V1, writes per-row stats (raw max, 1/sum).
__global__ __launch_bounds__(128, 2) void attn_stats_k(
    const bf16* __restrict__ Q, const bf16* __restrict__ Kb,
    const bf16* __restrict__ VT, bf16* __restrict__ obuf,
    float* __restrict__ mrow, float* __restrict__ rrow)
{
  __shared__ __align__(16) char plds[2*18432];
  const int t = threadIdx.x, w = t>>6, lane = t&63, g = lane>>4, r = lane&15;
  const int qt = blockIdx.x >> 7, bh = blockIdx.x & 127, b = bh >> 3, h = bh & 7;
  const int q0 = qt*32 + w*16;

  // S = Q K^T
  f32x4 s[36];
  #pragma unroll
  for (int n=0;n<36;++n) s[n] = (f32x4){0.f,0.f,0.f,0.f};
  bf16x8 aq[3];
  const bf16* qrow = Q + ((size_t)(b*N_ + q0 + r))*D_ + h*HD_;
  #pragma unroll
  for (int kk=0;kk<3;++kk) aq[kk] = *(const bf16x8*)(qrow + kk*32 + g*8);
  const bf16* kbase = Kb + ((size_t)b*N_ + r)*D_ + h*HD_ + g*8;
  #pragma unroll
  for (int n=0;n<36;++n) {
    const bf16* kr = kbase + (size_t)(n*16)*D_;
    #pragma unroll
    for (int kk=0;kk<3;++kk) {
      bf16x8 bk = *(const bf16x8*)(kr + kk*32);
      s[n] = __builtin_amdgcn_mfma_f32_16x16x32_bf16(aq[kk], bk, s[n], 0, 0, 0);
    }
  }

  // softmax
  float mx[4], rinv[4], sum[4];
  #pragma unroll
  for (int j=0;j<4;++j) {
    float m = -1e30f;
    #pragma unroll
    for (int n=0;n<36;++n) m = fmaxf(m, s[n][j]);
    #pragma unroll
    for (int d=1; d<16; d<<=1) m = fmaxf(m, __shfl_xor(m, d));
    mx[j] = m; sum[j] = 0.f;
  }
  #pragma unroll
  for (int n=0;n<36;++n)
    #pragma unroll
    for (int j=0;j<4;++j) {
      float p = __expf((s[n][j] - mx[j]) * SCALE_F);
      s[n][j] = p; sum[j] += p;
    }
  #pragma unroll
  for (int j=0;j<4;++j) {
    float ss = sum[j];
    #pragma unroll
    for (int d=1; d<16; d<<=1) ss += __shfl_xor(ss, d);
    rinv[j] = 1.0f / ss;
  }

  // stats out (raw max, 1/sum) — normal stores, re-read by attn_map_k soon
  if (r == 0) {
    const size_t sb = (size_t)bh*N_ + q0 + g*4;
    #pragma unroll
    for (int j=0;j<4;++j) { mrow[sb+j] = mx[j]; rrow[sb+j] = rinv[j]; }
  }

  // P (normalized, bf16) -> LDS fragment-linear [k8][row16]x16B
  char* pw = plds + w*18432;
  #pragma unroll
  for (int n=0;n<36;++n)
    #pragma unroll
    for (int j=0;j<4;++j) {
      int kc = n*16 + r, row = g*4+j;
      *(bf16*)(pw + ((kc>>3)<<8) + (row<<4) + ((kc&7)<<1)) = (bf16)(s[n][j]*rinv[j]);
    }
  __syncthreads();

  // O = P V   (V^T layout [B][D][N])
  f32x4 oa[6];
  #pragma unroll
  for (int n=0;n<6;++n) oa[n] = (f32x4){0.f,0.f,0.f,0.f};
  const bf16* vtb = VT + ((size_t)b*D_ + h*HD_ + r)*N_ + g*8;
  for (int kt=0; kt<18; ++kt) {
    bf16x8 pa = *(const bf16x8*)(pw + kt*1024 + lane*16);
    #pragma unroll
    for (int n=0;n<6;++n) {
      bf16x8 bv = *(const bf16x8*)(vtb + (size_t)(n*16)*N_ + kt*32);
      oa[n] = __builtin_amdgcn_mfma_f32_16x16x32_bf16(pa, bv, oa[n], 0, 0, 0);
    }
  }
  #pragma unroll
  for (int n=0;n<6;++n)
    #pragma unroll
    for (int j=0;j<4;++j) {
      int qr = q0 + g*4 + j;
      nt_bf16(obuf + ((size_t)b*N_ + qr)*D_ + h*HD_ + n*16 + r, oa[n][j]);
    }
}

// Kernel B (block s=0): O1 = softmax(Q1 K2^T) V2, plus the combined attention map:
// map[q,k] = 0.5*p1[q,k] + 0.5*exp((K1[q]·Q2[k] - m2[k])*scale)*rinv2[k]   (single nt write)
__global__ __launch_bounds__(128, 2) void attn_map_k(
    const bf16* __restrict__ Q1, const bf16* __restrict__ K2,
    const bf16* __restrict__ VT2, const bf16* __restrict__ K1,
    const bf16* __restrict__ Q2, const float* __restrict__ mrow,
    const float* __restrict__ rrow, float* __restrict__ attn_out,
    bf16* __restrict__ obuf)
{
  __shared__ __align__(16) char plds[2*18432];
  const int t = threadIdx.x, w = t>>6, lane = t&63, g = lane>>4, r = lane&15;
  const int qt = blockIdx.x >> 7, bh = blockIdx.x & 127, b = bh >> 3, h = bh & 7;
  const int q0 = qt*32 + w*16;

  // S1 = Q1 K2^T
  f32x4 s[36];
  #pragma unroll
  for (int n=0;n<36;++n) s[n] = (f32x4){0.f,0.f,0.f,0.f};
  bf16x8 aq[3];
  const bf16* qrow = Q1 + ((size_t)(b*N_ + q0 + r))*D_ + h*HD_;
  #pragma unroll
  for (int kk=0;kk<3;++kk) aq[kk] = *(const bf16x8*)(qrow + kk*32 + g*8);
  const bf16* kbase = K2 + ((size_t)b*N_ + r)*D_ + h*HD_ + g*8;
  #pragma unroll
  for (int n=0;n<36;++n) {
    const bf16* kr = kbase + (size_t)(n*16)*D_;
    #pragma unroll
    for (int kk=0;kk<3;++kk) {
      bf16x8 bk = *(const bf16x8*)(kr + kk*32);
      s[n] = __builtin_amdgcn_mfma_f32_16x16x32_bf16(aq[kk], bk, s[n], 0, 0, 0);
    }
  }

  // softmax (local rows — no stats needed)
  float mx[4], rinv[4], sum[4];
  #pragma unroll
  for (int j=0;j<4;++j) {
    float m = -1e30f;
    #pragma unroll
    for (int n=0;n<36;++n) m = fmaxf(m, s[n][j]);
    #pragma unroll
    for (int d=1; d<16; d<<=1) m = fmaxf(m, __shfl_xor(m, d));
    mx[j] = m; sum[j] = 0.f;
  }
  #pragma unroll
  for (int n=0;n<36;++n)
    #pragma unroll
    for (int j=0;j<4;++j) {
      float p = __expf((s[n][j] - mx[j]) * SCALE_F);
      s[n][j] = p; sum[j] += p;
    }
  #pragma unroll
  for (int j=0;j<4;++j) {
    float ss = sum[j];
    #pragma unroll
    for (int d=1; d<16; d<<=1) ss += __shfl_xor(ss, d);
    rinv[j] = 1.0f / ss;
  }

  // P1 (normalized bf16) -> LDS
  char* pw = plds + w*18432;
  #pragma unroll
  for (int n=0;n<36;++n)
    #pragma unroll
    for (int j=0;j<4;++j) {
      int kc = n*16 + r, row = g*4+j;
      *(bf16*)(pw + ((kc>>3)<<8) + (row<<4) + ((kc&7)<<1)) = (bf16)(s[n][j]*rinv[j]);
    }
  __syncthreads();

  // O1 = P1 V2
  f32x4 oa[6];
  #pragma unroll
  for (int n=0;n<6;++n) oa[n] = (f32x4){0.f,0.f,0.f,0.f};
  const bf16* vtb = VT2 + ((size_t)b*D_ + h*HD_ + r)*N_ + g*8;
  for (int kt=0; kt<18; ++kt) {
    bf16x8 pa = *(const bf16x8*)(pw + kt*1024 + lane*16);
    #pragma unroll
    for (int n=0;n<6;++n) {
      bf16x8 bv = *(const bf16x8*)(vtb + (size_t)(n*16)*N_ + kt*32);
      oa[n] = __builtin_amdgcn_mfma_f32_16x16x32_bf16(pa, bv, oa[n], 0, 0, 0);
    }
  }
  #pragma unroll
  for (int n=0;n<6;++n)
    #pragma unroll
    for (int j=0;j<4;++j) {
      int qr = q0 + g*4 + j;
      nt_bf16(obuf + ((size_t)b*N_ + qr)*D_ + h*HD_ + n*16 + r, oa[n][j]);
    }

  // T = K1[q-tile] · Q2^T   (T[q][k] = S2[k][q]); reuse s[] accs
  #pragma unroll
  for (int n=0;n<36;++n) s[n] = (f32x4){0.f,0.f,0.f,0.f};
  bf16x8 ak[3];
  const bf16* k1row = K1 + ((size_t)(b*N_ + q0 + r))*D_ + h*HD_;
  #pragma unroll
  for (int kk=0;kk<3;++kk) ak[kk] = *(const bf16x8*)(k1row + kk*32 + g*8);
  const bf16* q2b = Q2 + ((size_t)b*N_ + r)*D_ + h*HD_ + g*8;
  #pragma unroll
  for (int n=0;n<36;++n) {
    const bf16* qr2 = q2b + (size_t)(n*16)*D_;
    #pragma unroll
    for (int kk=0;kk<3;++kk) {
      bf16x8 bq2 = *(const bf16x8*)(qr2 + kk*32);
      s[n] = __builtin_amdgcn_mfma_f32_16x16x32_bf16(ak[kk], bq2, s[n], 0, 0, 0);
    }
  }

  // map = 0.5*(p1 + a2^T), single coalesced nt write
  const float* mb = mrow + (size_t)bh*N_;
  const float* rb = rrow + (size_t)bh*N_;
  float* aout = attn_out + (size_t)bh*N_*N_;
  #pragma unroll
  for (int n=0;n<36;++n) {
    const int kc = n*16 + r;
    const float m2v = mb[kc];
    const float rv  = rb[kc];
    #pragma unroll
    for (int j=0;j<4;++j) {
      const int row = g*4 + j;
      float p1 = (float)(*(const bf16*)(pw + ((kc>>3)<<8) + (row<<4) + ((kc&7)<<1)));
      float a2t = __expf((s[n][j] - m2v) * SCALE_F) * rv;
      nt_f32(aout + (size_t)(q0 + row)*N_ + kc, 0.5f*(p1 + a2t));
    }
  }
}

// ---------------- LayerNorm: out = LN(xres + y)*gamma + beta ----------------
template<int WRITE16>
__global__ __launch_bounds__(256) void ln_k(
    const float* __restrict__ xres, const float* __restrict__ y,
    const float* __restrict__ gamma, const float* __restrict__ beta,
    float* __restrict__ out32, bf16* __restrict__ out16)
{
  const int w = threadIdx.x>>6, lane = threadIdx.x&63;
  const size_t row = (size_t)blockIdx.x*4 + w;
  const float* xr = xres + row*D_;
  const float* yr = y    + row*D_;
  float v[12]; float s = 0.f, s2 = 0.f;
  #pragma unroll
  for (int i=0;i<3;++i) {
    f32x4 a  = *(const f32x4*)(xr + i*256 + lane*4);
    f32x4 bb = *(const f32x4*)(yr + i*256 + lane*4);
    #pragma unroll
    for (int q=0;q<4;++q) {
      float tq = a[q]+bb[q];
      v[i*4+q] = tq; s += tq; s2 += tq*tq;
    }
  }
  #pragma unroll
  for (int d=1; d<64; d<<=1) { s += __shfl_xor(s, d); s2 += __shfl_xor(s2, d); }
  const float mean = s*(1.f/D_);
  const float var  = s2*(1.f/D_) - mean*mean;
  const float rstd = rsqrtf(var + 1e-5f);
  #pragma unroll
  for (int i=0;i<3;++i) {
    int c = i*256 + lane*4;
    f32x4 gm = *(const f32x4*)(gamma + c);
    f32x4 bt = *(const f32x4*)(beta  + c);
    f32x4 o;
    #pragma unroll
    for (int q=0;q<4;++q) o[q] = (v[i*4+q]-mean)*rstd*gm[q] + bt[q];
    __builtin_nontemporal_store(o, (f32x4*)(out32 + row*D_ + c));
    if (WRITE16) {
      union { bf16 h[4]; unsigned long long q64; } u;
      u.h[0]=(bf16)o[0]; u.h[1]=(bf16)o[1]; u.h[2]=(bf16)o[2]; u.h[3]=(bf16)o[3];
      nt_u64(out16 + row*D_ + c, u.q64);
    }
  }
}

// ---------------- host ----------------
extern "C" void kernel_launch(void* const* d_in, const int* in_sizes, int n_in,
                              void* d_out, int out_size, void* d_ws, size_t ws_size,
                              hipStream_t stream)
{
  const float* x1  = (const float*)d_in[0];
  const float* x2  = (const float*)d_in[1];
  const float* Wq  = (const float*)d_in[2];  const float* bq  = (const float*)d_in[3];
  const float* Wk  = (const float*)d_in[4];  const float* bk  = (const float*)d_in[5];
  const float* Wv  = (const float*)d_in[6];  const float* bv  = (const float*)d_in[7];
  const float* Wo  = (const float*)d_in[8];  const float* bo  = (const float*)d_in[9];
  const float* g1  = (const float*)d_in[10]; const float* be1 = (const float*)d_in[11];
  const float* g2  = (const float*)d_in[12]; const float* be2 = (const float*)d_in[13];
  const float* W1  = (const float*)d_in[14]; const float* bf1 = (const float*)d_in[15];
  const float* W2  = (const float*)d_in[16]; const float* bf2 = (const float*)d_in[17];

  float* out1 = (float*)d_out;
  float* out2 = out1 + (size_t)R_*D_;
  float* attn = out2 + (size_t)R_*D_;

  char* ws = (char*)d_ws;
  size_t off = 0;
  auto alloc = [&](size_t bytes) -> void* {
    void* p = ws + off;
    off += (bytes + 255) & ~(size_t)255;
    return p;
  };
  const size_t RD2 = (size_t)R_*D_*2, RD4 = (size_t)R_*D_*4;
  bf16* xb0   = (bf16*)alloc(RD2);
  bf16* xb1   = (bf16*)alloc(RD2);
  bf16* wqkvT = (bf16*)alloc((size_t)2304*D_*2);
  float* bqkv = (float*)alloc(2304*4);
  bf16* woT   = (bf16*)alloc((size_t)D_*D_*2);
  bf16* w1T   = (bf16*)alloc((size_t)D_*DF_*2);
  bf16* w2T   = (bf16*)alloc((size_t)DF_*D_*2);
  size_t qkv_mark = off;                      // G aliases the QKV region later
  bf16* Q1  = (bf16*)alloc(RD2);
  bf16* K1  = (bf16*)alloc(RD2);
  bf16* VT1 = (bf16*)alloc(RD2);
  bf16* Q2  = (bf16*)alloc(RD2);
  bf16* K2  = (bf16*)alloc(RD2);
  bf16* VT2 = (bf16*)alloc(RD2);
  bf16* G   = (bf16*)(ws + qkv_mark);         // R x DF bf16 (56.6MB) fits in 6x14.2MB
  bf16* obuf1 = (bf16*)alloc(RD2);
  bf16* obuf2 = (bf16*)alloc(RD2);
  float* m2r  = (float*)alloc((size_t)B_*H_*N_*4);
  float* r2r  = (float*)alloc((size_t)B_*H_*N_*4);
  float* oproj = (float*)alloc(RD4);
  float* h32   = (float*)alloc(RD4);
  bf16*  h16   = (bf16*)alloc(RD2);
  (void)ws_size; (void)in_sizes; (void)n_in; (void)out_size;

  const int n4 = R_*D_/4;
  cast_f32_bf16_k<<<n4/256, 256, 0, stream>>>(x1, xb0, n4);
  cast_f32_bf16_k<<<n4/256, 256, 0, stream>>>(x2, xb1, n4);

  dim3 tb(32,8);
  // fused QKV weight: rows 0..767 = Wq^T, 768..1535 = Wk^T, 1536..2303 = Wv^T
  transpose_cast_k<<<dim3(24,24), tb, 0, stream>>>(Wq, wqkvT,             D_, D_);
  transpose_cast_k<<<dim3(24,24), tb, 0, stream>>>(Wk, wqkvT + 768*D_,    D_, D_);
  transpose_cast_k<<<dim3(24,24), tb, 0, stream>>>(Wv, wqkvT + 1536*D_,   D_, D_);
  transpose_cast_k<<<dim3(24,24), tb, 0, stream>>>(Wo, woT, D_, D_);
  transpose_cast_k<<<dim3(96,24), tb, 0, stream>>>(W1, w1T, D_, DF_);   // -> [3072][768]
  transpose_cast_k<<<dim3(24,96), tb, 0, stream>>>(W2, w2T, DF_, D_);   // -> [768][3072]
  concat_bias_k<<<9, 256, 0, stream>>>(bq, bk, bv, bqkv);

  // fused QKV projections (one GEMM per input)
  gemm_bt_k<4><<<dim3(72,18), 256, 0, stream>>>(xb0, wqkvT, bqkv, nullptr, Q1, K1, VT1, R_, 2304, D_);
  gemm_bt_k<4><<<dim3(72,18), 256, 0, stream>>>(xb1, wqkvT, bqkv, nullptr, Q2, K2, VT2, R_, 2304, D_);

  // attention: stats pass (block 2) then map pass (block 1 + combined map)
  attn_stats_k<<<2304, 128, 0, stream>>>(Q2, K1, VT1, obuf2, m2r, r2r);
  attn_map_k  <<<2304, 128, 0, stream>>>(Q1, K2, VT2, K1, Q2, m2r, r2r, attn, obuf1);

  // per-block tails
  const float* xf[2]  = { x1, x2 };
  bf16* ob[2]         = { obuf1, obuf2 };
  float* outp[2]      = { out1, out2 };
  for (int s = 0; s < 2; ++s) {
    gemm_bt_k<2><<<dim3(72,6),  256, 0, stream>>>(ob[s], woT, bo, oproj, nullptr, nullptr, nullptr, R_, D_, D_);
    ln_k<1><<<R_/4, 256, 0, stream>>>(xf[s], oproj, g1, be1, h32, h16);
    gemm_bt_k<3><<<dim3(72,24), 256, 0, stream>>>(h16, w1T, bf1, nullptr, G, nullptr, nullptr, R_, DF_, D_);
    gemm_bt_k<2><<<dim3(72,6),  256, 0, stream>>>(G,   w2T, bf2, oproj, nullptr, nullptr, nullptr, R_, D_, DF_);
    ln_k<0><<<R_/4, 256, 0, stream>>>(h32, oproj, g2, be2, outp[s], nullptr);
  }
}

// Round 3
// 1133.209 us; speedup vs baseline: 1.0762x; 1.0762x over previous
//
#include <hip/hip_runtime.h>
#include <cstdint>
#include <cstddef>

// Problem constants
#define B_   16
#define N_   576
#define D_   768
#define H_   8
#define HD_  96
#define DF_  3072
#define R_   (B_*N_)               // 9216 rows
#define SCALE_F 0.10206207261596575f  // 96^-0.5

typedef __bf16 bf16;
typedef __attribute__((ext_vector_type(8))) __bf16 bf16x8;
typedef __attribute__((ext_vector_type(4))) float  f32x4;

__device__ __forceinline__ void gld_lds16(const void* g, void* l) {
  __builtin_amdgcn_global_load_lds((const __attribute__((address_space(1))) void*)g,
                                   (__attribute__((address_space(3))) void*)l,
                                   16, 0, 0);
}
__device__ __forceinline__ void nt_f32(float* p, float v) { __builtin_nontemporal_store(v, p); }
__device__ __forceinline__ void nt_u64(void* p, unsigned long long v) { __builtin_nontemporal_store(v, (unsigned long long*)p); }
__device__ __forceinline__ void nt_bf16(bf16* p, float v) {
  bf16 h = (bf16)v; unsigned short u; __builtin_memcpy(&u, &h, 2);
  __builtin_nontemporal_store(u, (unsigned short*)p);
}

// ---------------- prep kernels ----------------
__global__ void cast_f32_bf16_k(const float* __restrict__ x, bf16* __restrict__ y, int n4) {
  int i = blockIdx.x*256 + threadIdx.x;
  if (i >= n4) return;
  f32x4 v = ((const f32x4*)x)[i];
  union { bf16 h[4]; unsigned long long q; } u;
  u.h[0] = (bf16)v[0]; u.h[1] = (bf16)v[1]; u.h[2] = (bf16)v[2]; u.h[3] = (bf16)v[3];
  nt_u64((unsigned long long*)y + i, u.q);
}

// WT[c][r] = (bf16)W[r][c];  rows, cols multiples of 32
__global__ void transpose_cast_k(const float* __restrict__ W, bf16* __restrict__ WT,
                                 int rows, int cols) {
  __shared__ float tile[32][33];
  int cb = blockIdx.x*32, rb = blockIdx.y*32;
  int tx = threadIdx.x, ty = threadIdx.y;   // block (32,8)
  #pragma unroll
  for (int i=0;i<32;i+=8)
    tile[ty+i][tx] = W[(size_t)(rb+ty+i)*cols + cb+tx];
  __syncthreads();
  #pragma unroll
  for (int i=0;i<32;i+=8)
    WT[(size_t)(cb+ty+i)*rows + rb+tx] = (bf16)tile[tx][ty+i];
}

__global__ void concat_bias_k(const float* a, const float* b, const float* c, float* o) {
  int i = blockIdx.x*256 + threadIdx.x;
  if (i < 768) o[i] = a[i];
  else if (i < 1536) o[i] = b[i-768];
  else if (i < 2304) o[i] = c[i-1536];
}

// ---------------- BT-GEMM: C[M,N] = A[M,K] @ Bt[N,K]^T + bias ----------------
// 128x128 tile, BK=64, 256 thr (4 waves 2x2), global_load_lds w=16,
// fragment-linear LDS layout: byte = blk16*2048 + k8*256 + r16*16  (zero bank conflicts)
// EPI: 2 = f32 out, 3 = gelu->bf16,
//      4 = fused QKV routing: Q,K -> head-separated [B][H][N][HD]; V -> V^T [B][D][N]
template<int EPI>
__global__ __launch_bounds__(256, 2) void gemm_bt_k(
    const bf16* __restrict__ A, const bf16* __restrict__ Bt,
    const float* __restrict__ bias, float* __restrict__ outF,
    bf16* __restrict__ outB, bf16* __restrict__ outK, bf16* __restrict__ outVT,
    int M, int Nn, int K)
{
  __shared__ __align__(16) char lds[32768];
  char* As = lds; char* Bs = lds + 16384;
  const int t = threadIdx.x;
  const int lane = t & 63, w = t >> 6, g = lane >> 4, r = lane & 15;
  const int wr = w >> 1, wc = w & 1;
  const int rt = blockIdx.x, ct = blockIdx.y;
  const size_t a0 = (size_t)rt*128, b0 = (size_t)ct*128;

  f32x4 acc[4][4];
  #pragma unroll
  for (int m=0;m<4;++m)
    #pragma unroll
    for (int n=0;n<4;++n) acc[m][n] = (f32x4){0.f,0.f,0.f,0.f};

  const int k8    = (t>>4)&7;
  const int rbase = ((t>>7)<<4) + (t&15);
  const bf16* Abase = A  + (a0 + rbase)*(size_t)K + k8*8;
  const bf16* Bbase = Bt + (b0 + rbase)*(size_t)K + k8*8;
  const size_t rstep = (size_t)32*K;
  const int nkb = K >> 6;

  for (int kb = 0; kb < nkb; ++kb) {
    const size_t ko = (size_t)kb*64;
    #pragma unroll
    for (int i=0;i<4;++i) {
      gld_lds16(Abase + (size_t)i*rstep + ko, As + i*4096 + t*16);
      gld_lds16(Bbase + (size_t)i*rstep + ko, Bs + i*4096 + t*16);
    }
    __syncthreads();
    #pragma unroll
    for (int kk=0;kk<2;++kk) {
      bf16x8 af[4], bfr[4];
      #pragma unroll
      for (int m=0;m<4;++m) af[m]  = *(const bf16x8*)(As + (wr*4+m)*2048 + kk*1024 + lane*16);
      #pragma unroll
      for (int n=0;n<4;++n) bfr[n] = *(const bf16x8*)(Bs + (wc*4+n)*2048 + kk*1024 + lane*16);
      #pragma unroll
      for (int m=0;m<4;++m)
        #pragma unroll
        for (int n=0;n<4;++n)
          acc[m][n] = __builtin_amdgcn_mfma_f32_16x16x32_bf16(af[m], bfr[n], acc[m][n], 0, 0, 0);
    }
    __syncthreads();
  }

  const int colb = ct*128 + wc*64;
  const int rowb = rt*128 + wr*64;
  #pragma unroll
  for (int n=0;n<4;++n) {
    const int col = colb + n*16 + r;
    const float bc = bias[col];
    #pragma unroll
    for (int m=0;m<4;++m) {
      const int row0 = rowb + m*16 + g*4;
      #pragma unroll
      for (int j=0;j<4;++j) {
        const int row = row0 + j;
        float v = acc[m][n][j] + bc;
        if (EPI == 2) {
          nt_f32(outF + (size_t)row*Nn + col, v);
        } else if (EPI == 3) {                  // exact gelu -> bf16
          float ge = 0.5f*v*(1.0f + erff(v*0.70710678118f));
          nt_bf16(outB + (size_t)row*Nn + col, ge);
        } else {                                // EPI==4: QKV routing
          const int bb = row / N_, nn = row - bb*N_;
          if (col < 768) {
            const int hh = col/96, dd = col - hh*96;
            nt_bf16(outB + ((size_t)(bb*H_+hh)*N_ + nn)*HD_ + dd, v);
          } else if (col < 1536) {
            const int c = col - 768, hh = c/96, dd = c - hh*96;
            nt_bf16(outK + ((size_t)(bb*H_+hh)*N_ + nn)*HD_ + dd, v);
          } else {
            nt_bf16(outVT + ((size_t)bb*D_ + (col-1536))*N_ + nn, v);
          }
        }
      }
    }
  }
  (void)M;
}

// ---------------- attention v3: column-split, 4 waves / 32 q-rows ----------------
// Grid 2304 = 18 qtiles x 128 bh; blockIdx&7 == h -> head-per-XCD L2 locality.
// Wave (wq, wc): 16 q-rows (wq), 288-col half (wc). s[18] accs (72 regs).
// Q,K head-separated [B][H][N][96]; VT [B][D][N].
// Softmax: per-wave 16-lane butterfly + cross-wave (wc pair) reduce via LDS.
// PV: output-d split by wc (3 accs), full 576 k from the wq P region.

// stats pass: O2 = softmax(Q2 K1^T) V1; writes combined row stats (raw max, 1/sum).
__global__ __launch_bounds__(256, 2) void attn_stats_k(
    const bf16* __restrict__ Q, const bf16* __restrict__ Kb,
    const bf16* __restrict__ VT, bf16* __restrict__ obuf,
    float* __restrict__ mrow, float* __restrict__ rrow)
{
  __shared__ __align__(16) char plds[2*18432 + 512];
  float* smax = (float*)(plds + 36864);          // [wq*2+wc][16]
  float* ssum = smax + 64;
  const int t = threadIdx.x, w = t>>6, lane = t&63, g = lane>>4, r = lane&15;
  const int wq = w>>1, wc = w&1;
  const int qt = blockIdx.x >> 7, bh = blockIdx.x & 127, b = bh>>3, h = bh&7;
  const int q0 = qt*32 + wq*16, c0 = wc*288, row4 = g*4;

  // S = Q K^T over col-half
  f32x4 s[18];
  #pragma unroll
  for (int n=0;n<18;++n) s[n] = (f32x4){0.f,0.f,0.f,0.f};
  bf16x8 aq[3];
  const bf16* qrow = Q + ((size_t)(b*H_+h)*N_ + q0 + r)*HD_;
  #pragma unroll
  for (int kk=0;kk<3;++kk) aq[kk] = *(const bf16x8*)(qrow + kk*32 + g*8);
  const bf16* kbase = Kb + ((size_t)(b*H_+h)*N_ + c0 + r)*HD_ + g*8;
  #pragma unroll
  for (int n=0;n<18;++n) {
    const bf16* kr = kbase + (size_t)(n*16)*HD_;
    #pragma unroll
    for (int kk=0;kk<3;++kk)
      s[n] = __builtin_amdgcn_mfma_f32_16x16x32_bf16(aq[kk], *(const bf16x8*)(kr + kk*32), s[n], 0, 0, 0);
  }

  // softmax with cross-wave reduce
  float mx[4], sum[4], rinv[4];
  #pragma unroll
  for (int j=0;j<4;++j) {
    float m = -1e30f;
    #pragma unroll
    for (int n=0;n<18;++n) m = fmaxf(m, s[n][j]);
    #pragma unroll
    for (int d=1; d<16; d<<=1) m = fmaxf(m, __shfl_xor(m, d));
    mx[j] = m;
  }
  if ((lane&15)==0) {
    #pragma unroll
    for (int j=0;j<4;++j) smax[(wq*2+wc)*16 + row4+j] = mx[j];
  }
  __syncthreads();
  #pragma unroll
  for (int j=0;j<4;++j) {
    mx[j] = fmaxf(mx[j], smax[(wq*2+(wc^1))*16 + row4+j]);
    sum[j] = 0.f;
  }
  #pragma unroll
  for (int n=0;n<18;++n)
    #pragma unroll
    for (int j=0;j<4;++j) {
      float p = __expf((s[n][j] - mx[j]) * SCALE_F);
      s[n][j] = p; sum[j] += p;
    }
  #pragma unroll
  for (int j=0;j<4;++j) {
    #pragma unroll
    for (int d=1; d<16; d<<=1) sum[j] += __shfl_xor(sum[j], d);
  }
  if ((lane&15)==0) {
    #pragma unroll
    for (int j=0;j<4;++j) ssum[(wq*2+wc)*16 + row4+j] = sum[j];
  }
  __syncthreads();
  #pragma unroll
  for (int j=0;j<4;++j)
    rinv[j] = 1.0f / (sum[j] + ssum[(wq*2+(wc^1))*16 + row4+j]);

  // combined stats out (once per row)
  if (wc==0 && (lane&15)==0) {
    const size_t sb = (size_t)bh*N_ + q0 + row4;
    #pragma unroll
    for (int j=0;j<4;++j) { mrow[sb+j] = mx[j]; rrow[sb+j] = rinv[j]; }
  }

  // P (normalized bf16) -> LDS fragment-linear, per-wq region
  char* pw = plds + wq*18432;
  #pragma unroll
  for (int n=0;n<18;++n)
    #pragma unroll
    for (int j=0;j<4;++j) {
      int kc = c0 + n*16 + r, row = row4 + j;
      *(bf16*)(pw + ((kc>>3)<<8) + (row<<4) + ((kc&7)<<1)) = (bf16)(s[n][j]*rinv[j]);
    }
  __syncthreads();

  // O = P V: d-tiles wc*3..wc*3+2, all 18 k-tiles
  f32x4 oa[3];
  #pragma unroll
  for (int n=0;n<3;++n) oa[n] = (f32x4){0.f,0.f,0.f,0.f};
  const bf16* vtb = VT + ((size_t)b*D_ + h*HD_ + wc*48 + r)*N_ + g*8;
  for (int kt=0; kt<18; ++kt) {
    bf16x8 pa = *(const bf16x8*)(pw + kt*1024 + lane*16);
    #pragma unroll
    for (int n=0;n<3;++n)
      oa[n] = __builtin_amdgcn_mfma_f32_16x16x32_bf16(pa, *(const bf16x8*)(vtb + (size_t)(n*16)*N_ + kt*32), oa[n], 0, 0, 0);
  }
  #pragma unroll
  for (int n=0;n<3;++n)
    #pragma unroll
    for (int j=0;j<4;++j)
      nt_bf16(obuf + ((size_t)b*N_ + q0+row4+j)*D_ + h*HD_ + wc*48 + n*16 + r, oa[n][j]);
}

// map pass: O1 = softmax(Q1 K2^T) V2 + combined map write
// map[q,k] = 0.5*p1[q,k] + 0.5*exp((K1[q]·Q2[k] - m2[k])*scale)*rinv2[k]
__global__ __launch_bounds__(256, 2) void attn_map_k(
    const bf16* __restrict__ Q1, const bf16* __restrict__ K2,
    const bf16* __restrict__ VT2, const bf16* __restrict__ K1,
    const bf16* __restrict__ Q2, const float* __restrict__ mrow,
    const float* __restrict__ rrow, float* __restrict__ attn_out,
    bf16* __restrict__ obuf)
{
  __shared__ __align__(16) char plds[2*18432 + 512];
  float* smax = (float*)(plds + 36864);
  float* ssum = smax + 64;
  const int t = threadIdx.x, w = t>>6, lane = t&63, g = lane>>4, r = lane&15;
  const int wq = w>>1, wc = w&1;
  const int qt = blockIdx.x >> 7, bh = blockIdx.x & 127, b = bh>>3, h = bh&7;
  const int q0 = qt*32 + wq*16, c0 = wc*288, row4 = g*4;

  // S1 = Q1 K2^T over col-half
  f32x4 s[18];
  #pragma unroll
  for (int n=0;n<18;++n) s[n] = (f32x4){0.f,0.f,0.f,0.f};
  bf16x8 aq[3];
  const bf16* qrow = Q1 + ((size_t)(b*H_+h)*N_ + q0 + r)*HD_;
  #pragma unroll
  for (int kk=0;kk<3;++kk) aq[kk] = *(const bf16x8*)(qrow + kk*32 + g*8);
  const bf16* kbase = K2 + ((size_t)(b*H_+h)*N_ + c0 + r)*HD_ + g*8;
  #pragma unroll
  for (int n=0;n<18;++n) {
    const bf16* kr = kbase + (size_t)(n*16)*HD_;
    #pragma unroll
    for (int kk=0;kk<3;++kk)
      s[n] = __builtin_amdgcn_mfma_f32_16x16x32_bf16(aq[kk], *(const bf16x8*)(kr + kk*32), s[n], 0, 0, 0);
  }

  // softmax
  float mx[4], sum[4], rinv[4];
  #pragma unroll
  for (int j=0;j<4;++j) {
    float m = -1e30f;
    #pragma unroll
    for (int n=0;n<18;++n) m = fmaxf(m, s[n][j]);
    #pragma unroll
    for (int d=1; d<16; d<<=1) m = fmaxf(m, __shfl_xor(m, d));
    mx[j] = m;
  }
  if ((lane&15)==0) {
    #pragma unroll
    for (int j=0;j<4;++j) smax[(wq*2+wc)*16 + row4+j] = mx[j];
  }
  __syncthreads();
  #pragma unroll
  for (int j=0;j<4;++j) {
    mx[j] = fmaxf(mx[j], smax[(wq*2+(wc^1))*16 + row4+j]);
    sum[j] = 0.f;
  }
  #pragma unroll
  for (int n=0;n<18;++n)
    #pragma unroll
    for (int j=0;j<4;++j) {
      float p = __expf((s[n][j] - mx[j]) * SCALE_F);
      s[n][j] = p; sum[j] += p;
    }
  #pragma unroll
  for (int j=0;j<4;++j) {
    #pragma unroll
    for (int d=1; d<16; d<<=1) sum[j] += __shfl_xor(sum[j], d);
  }
  if ((lane&15)==0) {
    #pragma unroll
    for (int j=0;j<4;++j) ssum[(wq*2+wc)*16 + row4+j] = sum[j];
  }
  __syncthreads();
  #pragma unroll
  for (int j=0;j<4;++j)
    rinv[j] = 1.0f / (sum[j] + ssum[(wq*2+(wc^1))*16 + row4+j]);

  // P1 -> LDS
  char* pw = plds + wq*18432;
  #pragma unroll
  for (int n=0;n<18;++n)
    #pragma unroll
    for (int j=0;j<4;++j) {
      int kc = c0 + n*16 + r, row = row4 + j;
      *(bf16*)(pw + ((kc>>3)<<8) + (row<<4) + ((kc&7)<<1)) = (bf16)(s[n][j]*rinv[j]);
    }
  __syncthreads();

  // O1 = P1 V2 (d-split)
  f32x4 oa[3];
  #pragma unroll
  for (int n=0;n<3;++n) oa[n] = (f32x4){0.f,0.f,0.f,0.f};
  const bf16* vtb = VT2 + ((size_t)b*D_ + h*HD_ + wc*48 + r)*N_ + g*8;
  for (int kt=0; kt<18; ++kt) {
    bf16x8 pa = *(const bf16x8*)(pw + kt*1024 + lane*16);
    #pragma unroll
    for (int n=0;n<3;++n)
      oa[n] = __builtin_amdgcn_mfma_f32_16x16x32_bf16(pa, *(const bf16x8*)(vtb + (size_t)(n*16)*N_ + kt*32), oa[n], 0, 0, 0);
  }
  #pragma unroll
  for (int n=0;n<3;++n)
    #pragma unroll
    for (int j=0;j<4;++j)
      nt_bf16(obuf + ((size_t)b*N_ + q0+row4+j)*D_ + h*HD_ + wc*48 + n*16 + r, oa[n][j]);

  // T = K1 Q2^T over col-half (T[q][k] = S2[k][q]); reuse s accs
  #pragma unroll
  for (int n=0;n<18;++n) s[n] = (f32x4){0.f,0.f,0.f,0.f};
  bf16x8 ak[3];
  const bf16* k1row = K1 + ((size_t)(b*H_+h)*N_ + q0 + r)*HD_;
  #pragma unroll
  for (int kk=0;kk<3;++kk) ak[kk] = *(const bf16x8*)(k1row + kk*32 + g*8);
  const bf16* q2b = Q2 + ((size_t)(b*H_+h)*N_ + c0 + r)*HD_ + g*8;
  #pragma unroll
  for (int n=0;n<18;++n) {
    const bf16* qr2 = q2b + (size_t)(n*16)*HD_;
    #pragma unroll
    for (int kk=0;kk<3;++kk)
      s[n] = __builtin_amdgcn_mfma_f32_16x16x32_bf16(ak[kk], *(const bf16x8*)(qr2 + kk*32), s[n], 0, 0, 0);
  }

  // map = 0.5*(p1 + a2^T), single coalesced nt write (col-half)
  const float* mb = mrow + (size_t)bh*N_;
  const float* rb = rrow + (size_t)bh*N_;
  float* aout = attn_out + (size_t)bh*N_*N_;
  #pragma unroll
  for (int n=0;n<18;++n) {
    const int kc = c0 + n*16 + r;
    const float m2v = mb[kc];
    const float rv  = rb[kc];
    #pragma unroll
    for (int j=0;j<4;++j) {
      const int row = row4 + j;
      float p1 = (float)(*(const bf16*)(pw + ((kc>>3)<<8) + (row<<4) + ((kc&7)<<1)));
      float a2t = __expf((s[n][j] - m2v) * SCALE_F) * rv;
      nt_f32(aout + (size_t)(q0 + row)*N_ + kc, 0.5f*(p1 + a2t));
    }
  }
}

// ---------------- LayerNorm: out = LN(xres + y)*gamma + beta ----------------
template<int WRITE16>
__global__ __launch_bounds__(256) void ln_k(
    const float* __restrict__ xres, const float* __restrict__ y,
    const float* __restrict__ gamma, const float* __restrict__ beta,
    float* __restrict__ out32, bf16* __restrict__ out16)
{
  const int w = threadIdx.x>>6, lane = threadIdx.x&63;
  const size_t row = (size_t)blockIdx.x*4 + w;
  const float* xr = xres + row*D_;
  const float* yr = y    + row*D_;
  float v[12]; float s = 0.f, s2 = 0.f;
  #pragma unroll
  for (int i=0;i<3;++i) {
    f32x4 a  = *(const f32x4*)(xr + i*256 + lane*4);
    f32x4 bb = *(const f32x4*)(yr + i*256 + lane*4);
    #pragma unroll
    for (int q=0;q<4;++q) {
      float tq = a[q]+bb[q];
      v[i*4+q] = tq; s += tq; s2 += tq*tq;
    }
  }
  #pragma unroll
  for (int d=1; d<64; d<<=1) { s += __shfl_xor(s, d); s2 += __shfl_xor(s2, d); }
  const float mean = s*(1.f/D_);
  const float var  = s2*(1.f/D_) - mean*mean;
  const float rstd = rsqrtf(var + 1e-5f);
  #pragma unroll
  for (int i=0;i<3;++i) {
    int c = i*256 + lane*4;
    f32x4 gm = *(const f32x4*)(gamma + c);
    f32x4 bt = *(const f32x4*)(beta  + c);
    f32x4 o;
    #pragma unroll
    for (int q=0;q<4;++q) o[q] = (v[i*4+q]-mean)*rstd*gm[q] + bt[q];
    __builtin_nontemporal_store(o, (f32x4*)(out32 + row*D_ + c));
    if (WRITE16) {
      union { bf16 h[4]; unsigned long long q64; } u;
      u.h[0]=(bf16)o[0]; u.h[1]=(bf16)o[1]; u.h[2]=(bf16)o[2]; u.h[3]=(bf16)o[3];
      nt_u64(out16 + row*D_ + c, u.q64);
    }
  }
}

// ---------------- host ----------------
extern "C" void kernel_launch(void* const* d_in, const int* in_sizes, int n_in,
                              void* d_out, int out_size, void* d_ws, size_t ws_size,
                              hipStream_t stream)
{
  const float* x1  = (const float*)d_in[0];
  const float* x2  = (const float*)d_in[1];
  const float* Wq  = (const float*)d_in[2];  const float* bq  = (const float*)d_in[3];
  const float* Wk  = (const float*)d_in[4];  const float* bk  = (const float*)d_in[5];
  const float* Wv  = (const float*)d_in[6];  const float* bv  = (const float*)d_in[7];
  const float* Wo  = (const float*)d_in[8];  const float* bo  = (const float*)d_in[9];
  const float* g1  = (const float*)d_in[10]; const float* be1 = (const float*)d_in[11];
  const float* g2  = (const float*)d_in[12]; const float* be2 = (const float*)d_in[13];
  const float* W1  = (const float*)d_in[14]; const float* bf1 = (const float*)d_in[15];
  const float* W2  = (const float*)d_in[16]; const float* bf2 = (const float*)d_in[17];

  float* out1 = (float*)d_out;
  float* out2 = out1 + (size_t)R_*D_;
  float* attn = out2 + (size_t)R_*D_;

  char* ws = (char*)d_ws;
  size_t off = 0;
  auto alloc = [&](size_t bytes) -> void* {
    void* p = ws + off;
    off += (bytes + 255) & ~(size_t)255;
    return p;
  };
  const size_t RD2 = (size_t)R_*D_*2, RD4 = (size_t)R_*D_*4;
  bf16* xb0   = (bf16*)alloc(RD2);
  bf16* xb1   = (bf16*)alloc(RD2);
  bf16* wqkvT = (bf16*)alloc((size_t)2304*D_*2);
  float* bqkv = (float*)alloc(2304*4);
  bf16* woT   = (bf16*)alloc((size_t)D_*D_*2);
  bf16* w1T   = (bf16*)alloc((size_t)D_*DF_*2);
  bf16* w2T   = (bf16*)alloc((size_t)DF_*D_*2);
  size_t qkv_mark = off;                      // G aliases the QKV region later
  bf16* Q1  = (bf16*)alloc(RD2);
  bf16* K1  = (bf16*)alloc(RD2);
  bf16* VT1 = (bf16*)alloc(RD2);
  bf16* Q2  = (bf16*)alloc(RD2);
  bf16* K2  = (bf16*)alloc(RD2);
  bf16* VT2 = (bf16*)alloc(RD2);
  bf16* G   = (bf16*)(ws + qkv_mark);         // R x DF bf16 fits in the 6 QKV buffers
  bf16* obuf1 = (bf16*)alloc(RD2);
  bf16* obuf2 = (bf16*)alloc(RD2);
  float* m2r  = (float*)alloc((size_t)B_*H_*N_*4);
  float* r2r  = (float*)alloc((size_t)B_*H_*N_*4);
  float* oproj = (float*)alloc(RD4);
  float* h32   = (float*)alloc(RD4);
  bf16*  h16   = (bf16*)alloc(RD2);
  (void)ws_size; (void)in_sizes; (void)n_in; (void)out_size;

  const int n4 = R_*D_/4;
  cast_f32_bf16_k<<<n4/256, 256, 0, stream>>>(x1, xb0, n4);
  cast_f32_bf16_k<<<n4/256, 256, 0, stream>>>(x2, xb1, n4);

  dim3 tb(32,8);
  // fused QKV weight: rows 0..767 = Wq^T, 768..1535 = Wk^T, 1536..2303 = Wv^T
  transpose_cast_k<<<dim3(24,24), tb, 0, stream>>>(Wq, wqkvT,             D_, D_);
  transpose_cast_k<<<dim3(24,24), tb, 0, stream>>>(Wk, wqkvT + 768*D_,    D_, D_);
  transpose_cast_k<<<dim3(24,24), tb, 0, stream>>>(Wv, wqkvT + 1536*D_,   D_, D_);
  transpose_cast_k<<<dim3(24,24), tb, 0, stream>>>(Wo, woT, D_, D_);
  transpose_cast_k<<<dim3(96,24), tb, 0, stream>>>(W1, w1T, D_, DF_);   // -> [3072][768]
  transpose_cast_k<<<dim3(24,96), tb, 0, stream>>>(W2, w2T, DF_, D_);   // -> [768][3072]
  concat_bias_k<<<9, 256, 0, stream>>>(bq, bk, bv, bqkv);

  // fused QKV projections (one GEMM per input)
  gemm_bt_k<4><<<dim3(72,18), 256, 0, stream>>>(xb0, wqkvT, bqkv, nullptr, Q1, K1, VT1, R_, 2304, D_);
  gemm_bt_k<4><<<dim3(72,18), 256, 0, stream>>>(xb1, wqkvT, bqkv, nullptr, Q2, K2, VT2, R_, 2304, D_);

  // attention: stats pass (block 2) then map pass (block 1 + combined map)
  attn_stats_k<<<2304, 256, 0, stream>>>(Q2, K1, VT1, obuf2, m2r, r2r);
  attn_map_k  <<<2304, 256, 0, stream>>>(Q1, K2, VT2, K1, Q2, m2r, r2r, attn, obuf1);

  // per-block tails
  const float* xf[2]  = { x1, x2 };
  bf16* ob[2]         = { obuf1, obuf2 };
  float* outp[2]      = { out1, out2 };
  for (int s = 0; s < 2; ++s) {
    gemm_bt_k<2><<<dim3(72,6),  256, 0, stream>>>(ob[s], woT, bo, oproj, nullptr, nullptr, nullptr, R_, D_, D_);
    ln_k<1><<<R_/4, 256, 0, stream>>>(xf[s], oproj, g1, be1, h32, h16);
    gemm_bt_k<3><<<dim3(72,24), 256, 0, stream>>>(h16, w1T, bf1, nullptr, G, nullptr, nullptr, R_, DF_, D_);
    gemm_bt_k<2><<<dim3(72,6),  256, 0, stream>>>(G,   w2T, bf2, oproj, nullptr, nullptr, nullptr, R_, D_, DF_);
    ln_k<0><<<R_/4, 256, 0, stream>>>(h32, oproj, g2, be2, outp[s], nullptr);
  }
}